// Round 1
// baseline (563.908 us; speedup 1.0000x reference)
//
#include <hip/hip_runtime.h>

// Problem constants (reference file)
#define GG 8
#define MPG 2048
#define KD 4096
#define ND 4096

using i32x4 = __attribute__((ext_vector_type(4))) int;

constexpr int BM = 128, BN = 128, BK = 64;

__device__ __forceinline__ int pack4(i32x4 v) {
  return (int)((unsigned)(v[0] & 0xff) | ((unsigned)(v[1] & 0xff) << 8) |
               ((unsigned)(v[2] & 0xff) << 16) | ((unsigned)(v[3] & 0xff) << 24));
}

// int32 -> int8 pack, 16 elements per thread per step
__global__ void conv_kernel(const int* __restrict__ src, char* __restrict__ dst, long nelem) {
  long t = (long)blockIdx.x * blockDim.x + threadIdx.x;
  long stride = (long)gridDim.x * blockDim.x;
  for (long e = t * 16; e < nelem; e += stride * 16) {
    i32x4 x0 = *(const i32x4*)(src + e);
    i32x4 x1 = *(const i32x4*)(src + e + 4);
    i32x4 x2 = *(const i32x4*)(src + e + 8);
    i32x4 x3 = *(const i32x4*)(src + e + 12);
    i32x4 p;
    p[0] = pack4(x0); p[1] = pack4(x1); p[2] = pack4(x2); p[3] = pack4(x3);
    *(i32x4*)(dst + e) = p;
  }
}

__device__ __forceinline__ void gload_lds16(const void* g, void* l) {
  __builtin_amdgcn_global_load_lds(
      (const __attribute__((address_space(1))) unsigned int*)g,
      (__attribute__((address_space(3))) unsigned int*)l, 16, 0, 0);
}

// Grouped i8 GEMM: C[g] = A[g] (MPG x K) * B[g]^T (N x K), tile 128x128, BK=64.
// DIRECT=true: read int32 inputs directly, pack in-kernel (fallback when ws too small).
template<bool DIRECT>
__global__ __launch_bounds__(256) void gemm_i8(
    const void* __restrict__ Aptr,
    const void* __restrict__ Bptr,
    const float* __restrict__ ls,
    const float* __restrict__ rs,
    float* __restrict__ out,
    int g0)
{
  __shared__ char lA[BM * BK];   // 8 KiB, linear row-major [128][64]
  __shared__ char lB[BN * BK];   // 8 KiB

  const int gl = blockIdx.z;
  const int g = g0 + gl;
  const int bm = blockIdx.y * BM;
  const int bn = blockIdx.x * BN;

  const int tid = threadIdx.x;
  const int lane = tid & 63;
  const int wave = tid >> 6;
  const int wr = (wave >> 1) * 64;   // wave's output sub-tile (2x2 waves, 64x64 each)
  const int wc = (wave & 1) * 64;

  const int r16 = lane & 15;
  const int kb = (lane >> 4) * 16;   // K byte offset of this lane's fragment slice

  i32x4 acc[4][4] = {};

  if constexpr (!DIRECT) {
    const char* Ag = (const char*)Aptr + ((size_t)gl * MPG + bm) * KD;
    const char* Bg = (const char*)Bptr + ((size_t)gl * ND + bn) * KD;
    // staging: thread t loads 16B: row = t>>2, kcol = (t&3)*16; lds linear off = t*16
    const int srow = tid >> 2;
    const int skoff = (tid & 3) * 16;
    const char* pa0 = Ag + (size_t)srow * KD + skoff;
    const char* pa1 = Ag + (size_t)(srow + 64) * KD + skoff;
    const char* pb0 = Bg + (size_t)srow * KD + skoff;
    const char* pb1 = Bg + (size_t)(srow + 64) * KD + skoff;
    char* la0 = lA + wave * 1024;          // wave-uniform LDS base; HW adds lane*16
    char* la1 = lA + 4096 + wave * 1024;
    char* lb0 = lB + wave * 1024;
    char* lb1 = lB + 4096 + wave * 1024;

    for (int k0 = 0; k0 < KD; k0 += BK) {
      gload_lds16(pa0 + k0, la0);
      gload_lds16(pa1 + k0, la1);
      gload_lds16(pb0 + k0, lb0);
      gload_lds16(pb1 + k0, lb1);
      __syncthreads();   // compiler emits s_waitcnt vmcnt(0) before s_barrier
      i32x4 af[4], bf[4];
#pragma unroll
      for (int m = 0; m < 4; ++m)
        af[m] = *(const i32x4*)(lA + (wr + m * 16 + r16) * BK + kb);
#pragma unroll
      for (int n = 0; n < 4; ++n)
        bf[n] = *(const i32x4*)(lB + (wc + n * 16 + r16) * BK + kb);
#pragma unroll
      for (int m = 0; m < 4; ++m)
#pragma unroll
        for (int n = 0; n < 4; ++n)
          acc[m][n] = __builtin_amdgcn_mfma_i32_16x16x64_i8(af[m], bf[n], acc[m][n], 0, 0, 0);
      __syncthreads();
    }
  } else {
    const int* Ag = (const int*)Aptr + ((size_t)gl * MPG + bm) * KD;
    const int* Bg = (const int*)Bptr + ((size_t)gl * ND + bn) * KD;
    const int drow = tid >> 1;        // 0..127
    const int dk = (tid & 1) * 32;    // half-row of BK=64

    for (int k0 = 0; k0 < KD; k0 += BK) {
      int pa[8], pb[8];
#pragma unroll
      for (int j = 0; j < 8; ++j)
        pa[j] = pack4(*(const i32x4*)(Ag + (size_t)drow * KD + k0 + dk + j * 4));
#pragma unroll
      for (int j = 0; j < 8; ++j)
        pb[j] = pack4(*(const i32x4*)(Bg + (size_t)drow * KD + k0 + dk + j * 4));
      __syncthreads();   // previous iter's LDS reads done before overwrite
      *(i32x4*)(lA + drow * 64 + dk)      = *(i32x4*)(pa);
      *(i32x4*)(lA + drow * 64 + dk + 16) = *(i32x4*)(pa + 4);
      *(i32x4*)(lB + drow * 64 + dk)      = *(i32x4*)(pb);
      *(i32x4*)(lB + drow * 64 + dk + 16) = *(i32x4*)(pb + 4);
      __syncthreads();
      i32x4 af[4], bf[4];
#pragma unroll
      for (int m = 0; m < 4; ++m)
        af[m] = *(const i32x4*)(lA + (wr + m * 16 + r16) * BK + kb);
#pragma unroll
      for (int n = 0; n < 4; ++n)
        bf[n] = *(const i32x4*)(lB + (wc + n * 16 + r16) * BK + kb);
#pragma unroll
      for (int m = 0; m < 4; ++m)
#pragma unroll
        for (int n = 0; n < 4; ++n)
          acc[m][n] = __builtin_amdgcn_mfma_i32_16x16x64_i8(af[m], bf[n], acc[m][n], 0, 0, 0);
    }
  }

  // Epilogue: C/D 16x16 layout: col = lane&15, row = (lane>>4)*4 + reg
  const size_t trow0 = (size_t)g * MPG + bm + wr + (lane >> 4) * 4;
  const int col0 = bn + wc + r16;
  float rsv[4];
#pragma unroll
  for (int n = 0; n < 4; ++n) rsv[n] = rs[(size_t)g * ND + col0 + n * 16];
#pragma unroll
  for (int m = 0; m < 4; ++m) {
#pragma unroll
    for (int r = 0; r < 4; ++r) {
      size_t row = trow0 + m * 16 + r;
      float lsv = ls[row];
#pragma unroll
      for (int n = 0; n < 4; ++n)
        out[row * ND + col0 + n * 16] = (float)acc[m][n][r] * lsv * rsv[n];
    }
  }
}

extern "C" void kernel_launch(void* const* d_in, const int* in_sizes, int n_in,
                              void* d_out, int out_size, void* d_ws, size_t ws_size,
                              hipStream_t stream) {
  const int* A32 = (const int*)d_in[0];       // (G*MPG, K) int8 values in int32
  const int* B32 = (const int*)d_in[1];       // (G, N, K) int8 values in int32
  const float* ls = (const float*)d_in[2];    // (G*MPG,)
  const float* rs = (const float*)d_in[3];    // (G, N)
  float* out = (float*)d_out;                 // (G*MPG, N) f32 (reference fp16 values)

  const size_t aE = (size_t)GG * MPG * KD;    // 67.1M
  const size_t bE = (size_t)GG * ND * KD;     // 134.2M
  const size_t aSlab = (size_t)MPG * KD;
  const size_t bSlab = (size_t)ND * KD;

  dim3 blk(256);
  if (d_ws && ws_size >= aE + bE) {
    // Full pre-convert, then one grouped GEMM launch.
    char* wsA = (char*)d_ws;
    char* wsB = wsA + aE;
    conv_kernel<<<8192, 256, 0, stream>>>(A32, wsA, (long)aE);
    conv_kernel<<<16384, 256, 0, stream>>>(B32, wsB, (long)bE);
    dim3 grid(ND / BN, MPG / BM, GG);
    gemm_i8<false><<<grid, blk, 0, stream>>>(wsA, wsB, ls, rs, out, 0);
  } else if (d_ws && ws_size >= aSlab + bSlab) {
    // Per-group convert + GEMM, ws reused (stream-ordered).
    char* wsA = (char*)d_ws;
    char* wsB = wsA + aSlab;
    for (int g = 0; g < GG; ++g) {
      conv_kernel<<<2048, 256, 0, stream>>>(A32 + (size_t)g * aSlab, wsA, (long)aSlab);
      conv_kernel<<<4096, 256, 0, stream>>>(B32 + (size_t)g * bSlab, wsB, (long)bSlab);
      dim3 grid(ND / BN, MPG / BM, 1);
      gemm_i8<false><<<grid, blk, 0, stream>>>(wsA, wsB, ls, rs, out, g);
    }
  } else {
    // No usable scratch: pack in-kernel from int32.
    dim3 grid(ND / BN, MPG / BM, GG);
    gemm_i8<true><<<grid, blk, 0, stream>>>(A32, B32, ls, rs, out, 0);
  }
}

// Round 3
// 499.490 us; speedup vs baseline: 1.1290x; 1.1290x over previous
//
#include <hip/hip_runtime.h>

// Problem constants (reference file)
#define GG 8
#define MPG 2048
#define KD 4096
#define ND 4096

using i32x4 = __attribute__((ext_vector_type(4))) int;

__device__ __forceinline__ int pack4(i32x4 v) {
  return (int)((unsigned)(v[0] & 0xff) | ((unsigned)(v[1] & 0xff) << 8) |
               ((unsigned)(v[2] & 0xff) << 16) | ((unsigned)(v[3] & 0xff) << 24));
}

// int32 -> int8 pack, 16 elements per thread per step (HBM-floor bound)
__global__ void conv_kernel(const int* __restrict__ src, char* __restrict__ dst, long nelem) {
  long t = (long)blockIdx.x * blockDim.x + threadIdx.x;
  long stride = (long)gridDim.x * blockDim.x;
  for (long e = t * 16; e < nelem; e += stride * 16) {
    i32x4 x0 = *(const i32x4*)(src + e);
    i32x4 x1 = *(const i32x4*)(src + e + 4);
    i32x4 x2 = *(const i32x4*)(src + e + 8);
    i32x4 x3 = *(const i32x4*)(src + e + 12);
    i32x4 p;
    p[0] = pack4(x0); p[1] = pack4(x1); p[2] = pack4(x2); p[3] = pack4(x3);
    *(i32x4*)(dst + e) = p;
  }
}

__device__ __forceinline__ void gload_lds16(const void* g, void* l) {
  __builtin_amdgcn_global_load_lds(
      (const __attribute__((address_space(1))) unsigned int*)g,
      (__attribute__((address_space(3))) unsigned int*)l, 16, 0, 0);
}

// ---------------------------------------------------------------------------
// 256x256 tile, BK=128 bytes (K=128 i8 = 2 MFMA K-steps), 8 waves (2Mx4N),
// 128 KiB LDS double buffer, T2 swizzle + counted vmcnt + setprio + XCD swizzle.
// ---------------------------------------------------------------------------
constexpr int NT = KD / 128;   // 32 K-tiles

__global__ __launch_bounds__(512, 2) void gemm256_i8(
    const char* __restrict__ Aall,   // (gl, MPG, KD) int8
    const char* __restrict__ Ball,   // (gl, ND, KD) int8
    const float* __restrict__ ls,
    const float* __restrict__ rs,
    float* __restrict__ out,
    int g0, int nwg)
{
  extern __shared__ char lds[];   // 131072 B: [2 buf][ A 32KB | B 32KB ]

  const int tid  = threadIdx.x;
  const int lane = tid & 63;
  const int wave = tid >> 6;

  // bijective XCD-aware swizzle (nwg % 8 == 0): contiguous chunk per XCD
  int bid = blockIdx.x;
  int wg  = (bid & 7) * (nwg >> 3) + (bid >> 3);
  const int gl = wg >> 7;              // 128 blocks per group (8my x 16nx)
  const int rr_ = wg & 127;
  const int bm = (rr_ >> 4) * 256;
  const int bn = (rr_ & 15) * 256;
  const int g  = g0 + gl;

  // ---- staging: thread t handles LDS-linear off = i*8192 + t*16 per matrix ----
  // row = i*64 + (t>>3), linear col = (t&7)*16; global col pre-inverse-swizzled.
  const int srow = tid >> 3;                                  // 0..63
  const int scol = ((tid & 7) << 4) ^ ((srow & 7) << 4);      // involution
  const char* Ag = Aall + ((size_t)gl * MPG + bm) * KD;
  const char* Bg = Ball + ((size_t)gl * ND  + bn) * KD;
  const char* pa[4]; const char* pb[4];
#pragma unroll
  for (int i = 0; i < 4; ++i) {
    pa[i] = Ag + (size_t)(i * 64 + srow) * KD + scol;
    pb[i] = Bg + (size_t)(i * 64 + srow) * KD + scol;
  }
  char* wbase = lds + wave * 1024;    // wave-uniform; HW adds lane*16

  auto stage = [&](int buf, int kt) {
    const int ko = kt << 7;
    char* d = wbase + buf * 65536;
#pragma unroll
    for (int i = 0; i < 4; ++i) gload_lds16(pa[i] + ko, d + i * 8192);
#pragma unroll
    for (int i = 0; i < 4; ++i) gload_lds16(pb[i] + ko, d + 32768 + i * 8192);
  };

  // ---- compute-side fragment addressing (swizzled read) ----
  const int wm = wave >> 2;            // 0..1  (M half)
  const int wn = wave & 3;             // 0..3  (N quarter)
  const int r16 = lane & 15;
  const int klane = (lane >> 4) << 4;          // 0,16,32,48 (K bytes within step)
  const int sx = (r16 & 7) << 4;               // swizzle XOR (row&7 == r16&7)
  const char* aBase0 = lds + (size_t)(wm * 128 + r16) * 128;
  const char* bBase0 = lds + 32768 + (size_t)(wn * 64 + r16) * 128;

  i32x4 acc[8][4] = {};

  auto compute = [&](int buf) {
    const char* pA = aBase0 + buf * 65536;
    const char* pB = bBase0 + buf * 65536;
#pragma unroll
    for (int ks = 0; ks < 2; ++ks) {
      const int kx = ((ks << 6) + klane) ^ sx;
      i32x4 bf[4], af[8];
#pragma unroll
      for (int n = 0; n < 4; ++n) bf[n] = *(const i32x4*)(pB + n * 2048 + kx);
#pragma unroll
      for (int m = 0; m < 8; ++m) af[m] = *(const i32x4*)(pA + m * 2048 + kx);
      __builtin_amdgcn_s_setprio(1);
#pragma unroll
      for (int m = 0; m < 8; ++m)
#pragma unroll
        for (int n = 0; n < 4; ++n)
          acc[m][n] = __builtin_amdgcn_mfma_i32_16x16x64_i8(af[m], bf[n], acc[m][n], 0, 0, 0);
      __builtin_amdgcn_s_setprio(0);
    }
  };

  // ---- main loop: 2-deep prefetch, counted vmcnt, raw barriers ----
  stage(0, 0);
  stage(1, 1);
#pragma unroll 1
  for (int kt = 0; kt < NT; ++kt) {
    const int cur = kt & 1;
    if (kt + 1 < NT) { asm volatile("s_waitcnt vmcnt(8)" ::: "memory"); }
    else             { asm volatile("s_waitcnt vmcnt(0)" ::: "memory"); }
    __builtin_amdgcn_s_barrier();
    asm volatile("" ::: "memory");     // keep ds_reads below the barrier
    compute(cur);
    asm volatile("" ::: "memory");     // keep ds_reads above the barrier
    __builtin_amdgcn_s_barrier();
    asm volatile("" ::: "memory");     // keep next stage's LDS writes below
    if (kt + 2 < NT) stage(cur, kt + 2);
  }

  // ---- epilogue: C/D layout col=lane&15, row=(lane>>4)*4+reg ----
  const size_t orow0 = (size_t)g * MPG + bm + wm * 128 + ((lane >> 4) << 2);
  const int col0 = bn + wn * 64 + r16;
  float rsv[4];
#pragma unroll
  for (int n = 0; n < 4; ++n) rsv[n] = rs[(size_t)g * ND + col0 + n * 16];
#pragma unroll
  for (int m = 0; m < 8; ++m) {
#pragma unroll
    for (int q = 0; q < 4; ++q) {
      size_t row = orow0 + m * 16 + q;
      float lsv = ls[row];
#pragma unroll
      for (int n = 0; n < 4; ++n)
        out[row * ND + col0 + n * 16] = (float)acc[m][n][q] * lsv * rsv[n];
    }
  }
}

// ---------------------------------------------------------------------------
// Fallback 128x128 kernel (round-1, known-good) for ws/attr contingencies.
// ---------------------------------------------------------------------------
constexpr int BM = 128, BN = 128, BK = 64;

template<bool DIRECT>
__global__ __launch_bounds__(256) void gemm_i8(
    const void* __restrict__ Aptr, const void* __restrict__ Bptr,
    const float* __restrict__ ls, const float* __restrict__ rs,
    float* __restrict__ out, int g0)
{
  __shared__ char lA[BM * BK];
  __shared__ char lB[BN * BK];

  const int gl = blockIdx.z;
  const int g = g0 + gl;
  const int bm = blockIdx.y * BM;
  const int bn = blockIdx.x * BN;
  const int tid = threadIdx.x;
  const int lane = tid & 63;
  const int wave = tid >> 6;
  const int wr = (wave >> 1) * 64;
  const int wc = (wave & 1) * 64;
  const int r16 = lane & 15;
  const int kb = (lane >> 4) * 16;

  i32x4 acc[4][4] = {};

  if constexpr (!DIRECT) {
    const char* Ag = (const char*)Aptr + ((size_t)gl * MPG + bm) * KD;
    const char* Bg = (const char*)Bptr + ((size_t)gl * ND + bn) * KD;
    const int srow = tid >> 2;
    const int skoff = (tid & 3) * 16;
    const char* pa0 = Ag + (size_t)srow * KD + skoff;
    const char* pa1 = Ag + (size_t)(srow + 64) * KD + skoff;
    const char* pb0 = Bg + (size_t)srow * KD + skoff;
    const char* pb1 = Bg + (size_t)(srow + 64) * KD + skoff;
    char* la0 = lA + wave * 1024;
    char* la1 = lA + 4096 + wave * 1024;
    char* lb0 = lB + wave * 1024;
    char* lb1 = lB + 4096 + wave * 1024;

    for (int k0 = 0; k0 < KD; k0 += BK) {
      gload_lds16(pa0 + k0, la0);
      gload_lds16(pa1 + k0, la1);
      gload_lds16(pb0 + k0, lb0);
      gload_lds16(pb1 + k0, lb1);
      __syncthreads();
      i32x4 af[4], bf[4];
#pragma unroll
      for (int m = 0; m < 4; ++m) af[m] = *(const i32x4*)(lA + (wr + m * 16 + r16) * BK + kb);
#pragma unroll
      for (int n = 0; n < 4; ++n) bf[n] = *(const i32x4*)(lB + (wc + n * 16 + r16) * BK + kb);
#pragma unroll
      for (int m = 0; m < 4; ++m)
#pragma unroll
        for (int n = 0; n < 4; ++n)
          acc[m][n] = __builtin_amdgcn_mfma_i32_16x16x64_i8(af[m], bf[n], acc[m][n], 0, 0, 0);
      __syncthreads();
    }
  } else {
    const int* Ag = (const int*)Aptr + ((size_t)gl * MPG + bm) * KD;
    const int* Bg = (const int*)Bptr + ((size_t)gl * ND + bn) * KD;
    const int drow = tid >> 1;
    const int dk = (tid & 1) * 32;

    for (int k0 = 0; k0 < KD; k0 += BK) {
      int pa[8], pb[8];
#pragma unroll
      for (int j = 0; j < 8; ++j) pa[j] = pack4(*(const i32x4*)(Ag + (size_t)drow * KD + k0 + dk + j * 4));
#pragma unroll
      for (int j = 0; j < 8; ++j) pb[j] = pack4(*(const i32x4*)(Bg + (size_t)drow * KD + k0 + dk + j * 4));
      __syncthreads();
      *(i32x4*)(lA + drow * 64 + dk)      = *(i32x4*)(pa);
      *(i32x4*)(lA + drow * 64 + dk + 16) = *(i32x4*)(pa + 4);
      *(i32x4*)(lB + drow * 64 + dk)      = *(i32x4*)(pb);
      *(i32x4*)(lB + drow * 64 + dk + 16) = *(i32x4*)(pb + 4);
      __syncthreads();
      i32x4 af[4], bf[4];
#pragma unroll
      for (int m = 0; m < 4; ++m) af[m] = *(const i32x4*)(lA + (wr + m * 16 + r16) * BK + kb);
#pragma unroll
      for (int n = 0; n < 4; ++n) bf[n] = *(const i32x4*)(lB + (wc + n * 16 + r16) * BK + kb);
#pragma unroll
      for (int m = 0; m < 4; ++m)
#pragma unroll
        for (int n = 0; n < 4; ++n)
          acc[m][n] = __builtin_amdgcn_mfma_i32_16x16x64_i8(af[m], bf[n], acc[m][n], 0, 0, 0);
    }
  }

  const size_t trow0 = (size_t)g * MPG + bm + wr + (lane >> 4) * 4;
  const int col0 = bn + wc + r16;
  float rsv[4];
#pragma unroll
  for (int n = 0; n < 4; ++n) rsv[n] = rs[(size_t)g * ND + col0 + n * 16];
#pragma unroll
  for (int m = 0; m < 4; ++m) {
#pragma unroll
    for (int q = 0; q < 4; ++q) {
      size_t row = trow0 + m * 16 + q;
      float lsv = ls[row];
#pragma unroll
      for (int n = 0; n < 4; ++n)
        out[row * ND + col0 + n * 16] = (float)acc[m][n][q] * lsv * rsv[n];
    }
  }
}

extern "C" void kernel_launch(void* const* d_in, const int* in_sizes, int n_in,
                              void* d_out, int out_size, void* d_ws, size_t ws_size,
                              hipStream_t stream) {
  const int* A32 = (const int*)d_in[0];
  const int* B32 = (const int*)d_in[1];
  const float* ls = (const float*)d_in[2];
  const float* rs = (const float*)d_in[3];
  float* out = (float*)d_out;

  const size_t aE = (size_t)GG * MPG * KD;
  const size_t bE = (size_t)GG * ND * KD;
  const size_t aSlab = (size_t)MPG * KD;
  const size_t bSlab = (size_t)ND * KD;

  const int smem = 131072;
  static_assert(131072 == 2 * (32768 + 32768), "lds layout");
  bool big_lds_ok =
      hipFuncSetAttribute((const void*)gemm256_i8,
                          hipFuncAttributeMaxDynamicSharedMemorySize, smem) == hipSuccess;

  if (d_ws && ws_size >= aE + bE) {
    char* wsA = (char*)d_ws;
    char* wsB = wsA + aE;
    conv_kernel<<<8192, 256, 0, stream>>>(A32, wsA, (long)aE);
    conv_kernel<<<16384, 256, 0, stream>>>(B32, wsB, (long)bE);
    if (big_lds_ok) {
      gemm256_i8<<<1024, 512, smem, stream>>>(wsA, wsB, ls, rs, out, 0, 1024);
    } else {
      dim3 grid(ND / BN, MPG / BM, GG);
      gemm_i8<false><<<grid, dim3(256), 0, stream>>>(wsA, wsB, ls, rs, out, 0);
    }
  } else if (d_ws && ws_size >= aSlab + bSlab) {
    char* wsA = (char*)d_ws;
    char* wsB = wsA + aSlab;
    for (int gidx = 0; gidx < GG; ++gidx) {
      conv_kernel<<<2048, 256, 0, stream>>>(A32 + (size_t)gidx * aSlab, wsA, (long)aSlab);
      conv_kernel<<<4096, 256, 0, stream>>>(B32 + (size_t)gidx * bSlab, wsB, (long)bSlab);
      if (big_lds_ok) {
        gemm256_i8<<<128, 512, smem, stream>>>(wsA, wsB, ls, rs, out, gidx, 128);
      } else {
        dim3 grid(ND / BN, MPG / BM, 1);
        gemm_i8<false><<<grid, dim3(256), 0, stream>>>(wsA, wsB, ls, rs, out, gidx);
      }
    }
  } else {
    dim3 grid(ND / BN, MPG / BM, GG);
    gemm_i8<true><<<grid, dim3(256), 0, stream>>>(A32, B32, ls, rs, out, 0);
  }
}

// Round 4
// 484.488 us; speedup vs baseline: 1.1639x; 1.0310x over previous
//
#include <hip/hip_runtime.h>

// Problem constants (reference file)
#define GG 8
#define MPG 2048
#define KD 4096
#define ND 4096

using i32x4 = __attribute__((ext_vector_type(4))) int;

__device__ __forceinline__ int pack4(i32x4 v) {
  return (int)((unsigned)(v[0] & 0xff) | ((unsigned)(v[1] & 0xff) << 8) |
               ((unsigned)(v[2] & 0xff) << 16) | ((unsigned)(v[3] & 0xff) << 24));
}

// int32 -> int8 pack, 16 elements per thread per step (HBM-floor bound)
__global__ void conv_kernel(const int* __restrict__ src, char* __restrict__ dst, long nelem) {
  long t = (long)blockIdx.x * blockDim.x + threadIdx.x;
  long stride = (long)gridDim.x * blockDim.x;
  for (long e = t * 16; e < nelem; e += stride * 16) {
    i32x4 x0 = *(const i32x4*)(src + e);
    i32x4 x1 = *(const i32x4*)(src + e + 4);
    i32x4 x2 = *(const i32x4*)(src + e + 8);
    i32x4 x3 = *(const i32x4*)(src + e + 12);
    i32x4 p;
    p[0] = pack4(x0); p[1] = pack4(x1); p[2] = pack4(x2); p[3] = pack4(x3);
    *(i32x4*)(dst + e) = p;
  }
}

__device__ __forceinline__ void gload_lds16(const void* g, void* l) {
  __builtin_amdgcn_global_load_lds(
      (const __attribute__((address_space(1))) unsigned int*)g,
      (__attribute__((address_space(3))) unsigned int*)l, 16, 0, 0);
}

#define CFENCE() asm volatile("" ::: "memory")

// ---------------------------------------------------------------------------
// 256x256 tile, BK=128 bytes (2 MFMA K-steps), 8 waves (2Mx4N), 128 KiB LDS
// double buffer. 4-phase interleave per K-tile (T3), T2 swizzle, counted-lead
// vmcnt gate (T4), setprio (T5), bijective XCD swizzle (T1).
// ---------------------------------------------------------------------------
constexpr int NT = KD / 128;   // 32 K-tiles

__global__ __launch_bounds__(512, 2) void gemm256_i8(
    const char* __restrict__ Aall,   // (gl, MPG, KD) int8
    const char* __restrict__ Ball,   // (gl, ND, KD) int8
    const float* __restrict__ ls,
    const float* __restrict__ rs,
    float* __restrict__ out,
    int g0, int nwg)
{
  extern __shared__ char lds[];   // 131072 B: [2 buf][ A 32KB | B 32KB ]

  const int tid  = threadIdx.x;
  const int lane = tid & 63;
  const int wave = tid >> 6;

  // bijective XCD-aware swizzle (nwg % 8 == 0): contiguous chunk per XCD
  int bid = blockIdx.x;
  int wg  = (bid & 7) * (nwg >> 3) + (bid >> 3);
  const int gl = wg >> 7;              // 128 blocks per group (8my x 16nx)
  const int rr_ = wg & 127;
  const int bm = (rr_ >> 4) * 256;
  const int bn = (rr_ & 15) * 256;
  const int g  = g0 + gl;

  // ---- staging: thread t covers LDS-linear off = i*8192 + t*16 per matrix ----
  // row = i*64 + (t>>3), linear col = (t&7)*16; global col pre-inverse-swizzled
  // (involution) so a swizzled ds_read returns linear data.
  const int srow = tid >> 3;                                  // 0..63
  const int scol = ((tid & 7) << 4) ^ ((srow & 7) << 4);
  const char* Ag = Aall + ((size_t)gl * MPG + bm) * KD;
  const char* Bg = Ball + ((size_t)gl * ND  + bn) * KD;
  const char* pa[4]; const char* pb[4];
#pragma unroll
  for (int i = 0; i < 4; ++i) {
    pa[i] = Ag + (size_t)(i * 64 + srow) * KD + scol;
    pb[i] = Bg + (size_t)(i * 64 + srow) * KD + scol;
  }
  char* wbase = lds + wave * 1024;    // wave-uniform; HW adds lane*16

  auto stageA = [&](int buf, int kt) {
    const int ko = kt << 7;
    char* d = wbase + buf * 65536;
#pragma unroll
    for (int i = 0; i < 4; ++i) gload_lds16(pa[i] + ko, d + i * 8192);
  };
  auto stageB = [&](int buf, int kt) {
    const int ko = kt << 7;
    char* d = wbase + buf * 65536 + 32768;
#pragma unroll
    for (int i = 0; i < 4; ++i) gload_lds16(pb[i] + ko, d + i * 8192);
  };

  // ---- compute-side fragment addressing (swizzled read) ----
  const int wm = wave >> 2;            // 0..1  (M half)
  const int wn = wave & 3;             // 0..3  (N quarter)
  const int r16 = lane & 15;
  const int klane = (lane >> 4) << 4;          // 0,16,32,48 (K bytes in step)
  const int sx = (r16 & 7) << 4;               // swizzle XOR (row&7 == r16&7)
  const char* aBase0 = lds + (size_t)(wm * 128 + r16) * 128;
  const char* bBase0 = lds + 32768 + (size_t)(wn * 64 + r16) * 128;

  i32x4 acc[8][4] = {};

  // ---- prologue: stage tile 0, gate, barrier ----
  stageA(0, 0); stageB(0, 0);
  asm volatile("s_waitcnt vmcnt(0)" ::: "memory");
  __builtin_amdgcn_s_barrier();
  CFENCE();

  // ---- main loop: 4 phases per K-tile of 16 MFMA each ----
#pragma unroll 1
  for (int kt = 0; kt < NT; ++kt) {
    const int c = kt & 1;
    const char* pA = aBase0 + c * 65536;
    const char* pB = bBase0 + c * 65536;
    const int kx0 = klane ^ sx;
    const int kx1 = (64 + klane) ^ sx;
    const bool pre = (kt + 1 < NT);
    i32x4 af[4], bf[4];

    // ---- phase 1: {af m0-3, bf} @ks0 ; stage A(kt+1) -> buf c^1 ----
#pragma unroll
    for (int n = 0; n < 4; ++n) bf[n] = *(const i32x4*)(pB + n * 2048 + kx0);
#pragma unroll
    for (int m = 0; m < 4; ++m) af[m] = *(const i32x4*)(pA + m * 2048 + kx0);
    if (pre) stageA(c ^ 1, kt + 1);
    CFENCE(); __builtin_amdgcn_s_barrier(); CFENCE();
    __builtin_amdgcn_s_setprio(1);
#pragma unroll
    for (int m = 0; m < 4; ++m)
#pragma unroll
      for (int n = 0; n < 4; ++n)
        acc[m][n] = __builtin_amdgcn_mfma_i32_16x16x64_i8(af[m], bf[n], acc[m][n], 0, 0, 0);
    __builtin_amdgcn_s_setprio(0);
    CFENCE(); __builtin_amdgcn_s_barrier(); CFENCE();

    // ---- phase 2: {af m4-7} @ks0 (bf reused) ; stage B(kt+1) ----
#pragma unroll
    for (int m = 0; m < 4; ++m) af[m] = *(const i32x4*)(pA + (4 + m) * 2048 + kx0);
    if (pre) stageB(c ^ 1, kt + 1);
    CFENCE(); __builtin_amdgcn_s_barrier(); CFENCE();
    __builtin_amdgcn_s_setprio(1);
#pragma unroll
    for (int m = 0; m < 4; ++m)
#pragma unroll
      for (int n = 0; n < 4; ++n)
        acc[4 + m][n] = __builtin_amdgcn_mfma_i32_16x16x64_i8(af[m], bf[n], acc[4 + m][n], 0, 0, 0);
    __builtin_amdgcn_s_setprio(0);
    CFENCE(); __builtin_amdgcn_s_barrier(); CFENCE();

    // ---- phase 3: {af m0-3, bf} @ks1 ----
#pragma unroll
    for (int n = 0; n < 4; ++n) bf[n] = *(const i32x4*)(pB + n * 2048 + kx1);
#pragma unroll
    for (int m = 0; m < 4; ++m) af[m] = *(const i32x4*)(pA + m * 2048 + kx1);
    CFENCE(); __builtin_amdgcn_s_barrier(); CFENCE();
    __builtin_amdgcn_s_setprio(1);
#pragma unroll
    for (int m = 0; m < 4; ++m)
#pragma unroll
      for (int n = 0; n < 4; ++n)
        acc[m][n] = __builtin_amdgcn_mfma_i32_16x16x64_i8(af[m], bf[n], acc[m][n], 0, 0, 0);
    __builtin_amdgcn_s_setprio(0);
    CFENCE(); __builtin_amdgcn_s_barrier(); CFENCE();

    // ---- phase 4: {af m4-7} @ks1 ; vmcnt gate for tile kt+1 ----
#pragma unroll
    for (int m = 0; m < 4; ++m) af[m] = *(const i32x4*)(pA + (4 + m) * 2048 + kx1);
    asm volatile("s_waitcnt vmcnt(0)" ::: "memory");   // loads had 2-3 phase lead
    CFENCE(); __builtin_amdgcn_s_barrier(); CFENCE();
    __builtin_amdgcn_s_setprio(1);
#pragma unroll
    for (int m = 0; m < 4; ++m)
#pragma unroll
      for (int n = 0; n < 4; ++n)
        acc[4 + m][n] = __builtin_amdgcn_mfma_i32_16x16x64_i8(af[m], bf[n], acc[4 + m][n], 0, 0, 0);
    __builtin_amdgcn_s_setprio(0);
    CFENCE(); __builtin_amdgcn_s_barrier(); CFENCE();
  }

  // ---- epilogue: C/D layout col=lane&15, row=(lane>>4)*4+reg ----
  const size_t orow0 = (size_t)g * MPG + bm + wm * 128 + ((lane >> 4) << 2);
  const int col0 = bn + wn * 64 + r16;
  float rsv[4];
#pragma unroll
  for (int n = 0; n < 4; ++n) rsv[n] = rs[(size_t)g * ND + col0 + n * 16];
#pragma unroll
  for (int m = 0; m < 8; ++m) {
#pragma unroll
    for (int q = 0; q < 4; ++q) {
      size_t row = orow0 + m * 16 + q;
      float lsv = ls[row];
#pragma unroll
      for (int n = 0; n < 4; ++n)
        out[row * ND + col0 + n * 16] = (float)acc[m][n][q] * lsv * rsv[n];
    }
  }
}

// ---------------------------------------------------------------------------
// Fallback 128x128 kernel (round-1, known-good) for ws/attr contingencies.
// ---------------------------------------------------------------------------
constexpr int BM = 128, BN = 128, BK = 64;

template<bool DIRECT>
__global__ __launch_bounds__(256) void gemm_i8(
    const void* __restrict__ Aptr, const void* __restrict__ Bptr,
    const float* __restrict__ ls, const float* __restrict__ rs,
    float* __restrict__ out, int g0)
{
  __shared__ char lA[BM * BK];
  __shared__ char lB[BN * BK];

  const int gl = blockIdx.z;
  const int g = g0 + gl;
  const int bm = blockIdx.y * BM;
  const int bn = blockIdx.x * BN;
  const int tid = threadIdx.x;
  const int lane = tid & 63;
  const int wave = tid >> 6;
  const int wr = (wave >> 1) * 64;
  const int wc = (wave & 1) * 64;
  const int r16 = lane & 15;
  const int kb = (lane >> 4) * 16;

  i32x4 acc[4][4] = {};

  if constexpr (!DIRECT) {
    const char* Ag = (const char*)Aptr + ((size_t)gl * MPG + bm) * KD;
    const char* Bg = (const char*)Bptr + ((size_t)gl * ND + bn) * KD;
    const int srow = tid >> 2;
    const int skoff = (tid & 3) * 16;
    const char* pa0 = Ag + (size_t)srow * KD + skoff;
    const char* pa1 = Ag + (size_t)(srow + 64) * KD + skoff;
    const char* pb0 = Bg + (size_t)srow * KD + skoff;
    const char* pb1 = Bg + (size_t)(srow + 64) * KD + skoff;
    char* la0 = lA + wave * 1024;
    char* la1 = lA + 4096 + wave * 1024;
    char* lb0 = lB + wave * 1024;
    char* lb1 = lB + 4096 + wave * 1024;

    for (int k0 = 0; k0 < KD; k0 += BK) {
      gload_lds16(pa0 + k0, la0);
      gload_lds16(pa1 + k0, la1);
      gload_lds16(pb0 + k0, lb0);
      gload_lds16(pb1 + k0, lb1);
      __syncthreads();
      i32x4 af[4], bf[4];
#pragma unroll
      for (int m = 0; m < 4; ++m) af[m] = *(const i32x4*)(lA + (wr + m * 16 + r16) * BK + kb);
#pragma unroll
      for (int n = 0; n < 4; ++n) bf[n] = *(const i32x4*)(lB + (wc + n * 16 + r16) * BK + kb);
#pragma unroll
      for (int m = 0; m < 4; ++m)
#pragma unroll
        for (int n = 0; n < 4; ++n)
          acc[m][n] = __builtin_amdgcn_mfma_i32_16x16x64_i8(af[m], bf[n], acc[m][n], 0, 0, 0);
      __syncthreads();
    }
  } else {
    const int* Ag = (const int*)Aptr + ((size_t)gl * MPG + bm) * KD;
    const int* Bg = (const int*)Bptr + ((size_t)gl * ND + bn) * KD;
    const int drow = tid >> 1;
    const int dk = (tid & 1) * 32;

    for (int k0 = 0; k0 < KD; k0 += BK) {
      int pa[8], pb[8];
#pragma unroll
      for (int j = 0; j < 8; ++j) pa[j] = pack4(*(const i32x4*)(Ag + (size_t)drow * KD + k0 + dk + j * 4));
#pragma unroll
      for (int j = 0; j < 8; ++j) pb[j] = pack4(*(const i32x4*)(Bg + (size_t)drow * KD + k0 + dk + j * 4));
      __syncthreads();
      *(i32x4*)(lA + drow * 64 + dk)      = *(i32x4*)(pa);
      *(i32x4*)(lA + drow * 64 + dk + 16) = *(i32x4*)(pa + 4);
      *(i32x4*)(lB + drow * 64 + dk)      = *(i32x4*)(pb);
      *(i32x4*)(lB + drow * 64 + dk + 16) = *(i32x4*)(pb + 4);
      __syncthreads();
      i32x4 af[4], bf[4];
#pragma unroll
      for (int m = 0; m < 4; ++m) af[m] = *(const i32x4*)(lA + (wr + m * 16 + r16) * BK + kb);
#pragma unroll
      for (int n = 0; n < 4; ++n) bf[n] = *(const i32x4*)(lB + (wc + n * 16 + r16) * BK + kb);
#pragma unroll
      for (int m = 0; m < 4; ++m)
#pragma unroll
        for (int n = 0; n < 4; ++n)
          acc[m][n] = __builtin_amdgcn_mfma_i32_16x16x64_i8(af[m], bf[n], acc[m][n], 0, 0, 0);
    }
  }

  const size_t trow0 = (size_t)g * MPG + bm + wr + (lane >> 4) * 4;
  const int col0 = bn + wc + r16;
  float rsv[4];
#pragma unroll
  for (int n = 0; n < 4; ++n) rsv[n] = rs[(size_t)g * ND + col0 + n * 16];
#pragma unroll
  for (int m = 0; m < 4; ++m) {
#pragma unroll
    for (int q = 0; q < 4; ++q) {
      size_t row = trow0 + m * 16 + q;
      float lsv = ls[row];
#pragma unroll
      for (int n = 0; n < 4; ++n)
        out[row * ND + col0 + n * 16] = (float)acc[m][n][q] * lsv * rsv[n];
    }
  }
}

extern "C" void kernel_launch(void* const* d_in, const int* in_sizes, int n_in,
                              void* d_out, int out_size, void* d_ws, size_t ws_size,
                              hipStream_t stream) {
  const int* A32 = (const int*)d_in[0];
  const int* B32 = (const int*)d_in[1];
  const float* ls = (const float*)d_in[2];
  const float* rs = (const float*)d_in[3];
  float* out = (float*)d_out;

  const size_t aE = (size_t)GG * MPG * KD;
  const size_t bE = (size_t)GG * ND * KD;
  const size_t aSlab = (size_t)MPG * KD;
  const size_t bSlab = (size_t)ND * KD;

  const int smem = 131072;
  bool big_lds_ok =
      hipFuncSetAttribute((const void*)gemm256_i8,
                          hipFuncAttributeMaxDynamicSharedMemorySize, smem) == hipSuccess;

  if (d_ws && ws_size >= aE + bE) {
    char* wsA = (char*)d_ws;
    char* wsB = wsA + aE;
    conv_kernel<<<8192, 256, 0, stream>>>(A32, wsA, (long)aE);
    conv_kernel<<<16384, 256, 0, stream>>>(B32, wsB, (long)bE);
    if (big_lds_ok) {
      gemm256_i8<<<1024, 512, smem, stream>>>(wsA, wsB, ls, rs, out, 0, 1024);
    } else {
      dim3 grid(ND / BN, MPG / BM, GG);
      gemm_i8<false><<<grid, dim3(256), 0, stream>>>(wsA, wsB, ls, rs, out, 0);
    }
  } else if (d_ws && ws_size >= aSlab + bSlab) {
    char* wsA = (char*)d_ws;
    char* wsB = wsA + aSlab;
    for (int gidx = 0; gidx < GG; ++gidx) {
      conv_kernel<<<2048, 256, 0, stream>>>(A32 + (size_t)gidx * aSlab, wsA, (long)aSlab);
      conv_kernel<<<4096, 256, 0, stream>>>(B32 + (size_t)gidx * bSlab, wsB, (long)bSlab);
      if (big_lds_ok) {
        gemm256_i8<<<128, 512, smem, stream>>>(wsA, wsB, ls, rs, out, gidx, 128);
      } else {
        dim3 grid(ND / BN, MPG / BM, 1);
        gemm_i8<false><<<grid, dim3(256), 0, stream>>>(wsA, wsB, ls, rs, out, gidx);
      }
    }
  } else {
    dim3 grid(ND / BN, MPG / BM, GG);
    gemm_i8<true><<<grid, dim3(256), 0, stream>>>(A32, B32, ls, rs, out, 0);
  }
}